// Round 7
// baseline (397.207 us; speedup 1.0000x reference)
//
#include <hip/hip_runtime.h>

// Householder reflection: out[b,:] = z[b,:] - 2*v[b,:]*(v.z)/(v.v)
// B=8192 rows, L=4096 fp32.
// R0/R3/R4/R6 all pin at ~110-122us / ~2.4 TB/s HBM regardless of structure.
// Little's-law post-mortem: every version had the same waves*outstanding
// product (R0 16 coupled waves, R3 24 barrier-locked waves = 3 streams,
// R6 8.6 free waves at 27% occupancy). Known-good reference: LayerNorm /
// RMSNorm (same reduce-then-scale shape) hit 82-86% of HBM BW on this chip
// at HIGH occupancy with streaming TLP (m219/m238).
// This version: wave-per-row, ZERO staging. Pass 1 streams v,z through
// accumulators; pass 2 RE-READS v,z (row is L2/L3-hot - the compiler already
// chose re-reading z on its own in R6). Working set ~50 VGPR;
// __launch_bounds__(256,8) caps VGPR at 64 -> 8 waves/SIMD = 32 independent
// row-streams per CU (3.7x R6). No LDS, no barriers.

#define L_DIM 4096
#define BLOCK 256
#define WPB (BLOCK / 64)                // 4 waves (= rows) per block
#define NF4 (L_DIM / 4 / 64)            // 16 float4 per lane per array

typedef float f4 __attribute__((ext_vector_type(4)));

__global__ __launch_bounds__(BLOCK, 8) void householder_kernel(
    const float* __restrict__ v,
    const float* __restrict__ z,
    float* __restrict__ out,
    int B)
{
    const int wave = threadIdx.x >> 6;
    const int lane = threadIdx.x & 63;
    const int row = blockIdx.x * WPB + wave;
    if (row >= B) return;

    const size_t base = (size_t)row * L_DIM;
    const f4* v4 = (const f4*)(v + base);
    const f4* z4 = (const f4*)(z + base);
    f4* o4 = (f4*)(out + base);

    // Pass 1: stream the row through 4 accumulator pairs. Nothing staged —
    // 8 loads per iteration, consumed as they arrive. Coalesced 1 KiB/instr.
    float vz0 = 0.f, vz1 = 0.f, vz2 = 0.f, vz3 = 0.f;
    float vv0 = 0.f, vv1 = 0.f, vv2 = 0.f, vv3 = 0.f;
    for (int j = 0; j < NF4; j += 4) {
        f4 a0 = v4[lane + (j+0)*64]; f4 b0 = z4[lane + (j+0)*64];
        f4 a1 = v4[lane + (j+1)*64]; f4 b1 = z4[lane + (j+1)*64];
        f4 a2 = v4[lane + (j+2)*64]; f4 b2 = z4[lane + (j+2)*64];
        f4 a3 = v4[lane + (j+3)*64]; f4 b3 = z4[lane + (j+3)*64];

        vz0 = fmaf(a0.x, b0.x, vz0); vz0 = fmaf(a0.y, b0.y, vz0);
        vz0 = fmaf(a0.z, b0.z, vz0); vz0 = fmaf(a0.w, b0.w, vz0);
        vv0 = fmaf(a0.x, a0.x, vv0); vv0 = fmaf(a0.y, a0.y, vv0);
        vv0 = fmaf(a0.z, a0.z, vv0); vv0 = fmaf(a0.w, a0.w, vv0);

        vz1 = fmaf(a1.x, b1.x, vz1); vz1 = fmaf(a1.y, b1.y, vz1);
        vz1 = fmaf(a1.z, b1.z, vz1); vz1 = fmaf(a1.w, b1.w, vz1);
        vv1 = fmaf(a1.x, a1.x, vv1); vv1 = fmaf(a1.y, a1.y, vv1);
        vv1 = fmaf(a1.z, a1.z, vv1); vv1 = fmaf(a1.w, a1.w, vv1);

        vz2 = fmaf(a2.x, b2.x, vz2); vz2 = fmaf(a2.y, b2.y, vz2);
        vz2 = fmaf(a2.z, b2.z, vz2); vz2 = fmaf(a2.w, b2.w, vz2);
        vv2 = fmaf(a2.x, a2.x, vv2); vv2 = fmaf(a2.y, a2.y, vv2);
        vv2 = fmaf(a2.z, a2.z, vv2); vv2 = fmaf(a2.w, a2.w, vv2);

        vz3 = fmaf(a3.x, b3.x, vz3); vz3 = fmaf(a3.y, b3.y, vz3);
        vz3 = fmaf(a3.z, b3.z, vz3); vz3 = fmaf(a3.w, b3.w, vz3);
        vv3 = fmaf(a3.x, a3.x, vv3); vv3 = fmaf(a3.y, a3.y, vv3);
        vv3 = fmaf(a3.w, a3.w, vv3); vv3 = fmaf(a3.z, a3.z, vv3);
    }
    float vz = (vz0 + vz1) + (vz2 + vz3);
    float vv = (vv0 + vv1) + (vv2 + vv3);

    // Wave-wide butterfly reduction: all 64 lanes end with the full sums.
    #pragma unroll
    for (int off = 32; off > 0; off >>= 1) {
        vz += __shfl_xor(vz, off, 64);
        vv += __shfl_xor(vv, off, 64);
    }
    const float s = -2.0f * vz / vv;

    // Pass 2: re-read the row (L2/L3-hot), apply reflection, store.
    for (int j = 0; j < NF4; j += 4) {
        f4 a0 = v4[lane + (j+0)*64]; f4 b0 = z4[lane + (j+0)*64];
        f4 a1 = v4[lane + (j+1)*64]; f4 b1 = z4[lane + (j+1)*64];
        f4 a2 = v4[lane + (j+2)*64]; f4 b2 = z4[lane + (j+2)*64];
        f4 a3 = v4[lane + (j+3)*64]; f4 b3 = z4[lane + (j+3)*64];

        f4 r0, r1, r2, r3;
        r0.x = fmaf(s, a0.x, b0.x); r0.y = fmaf(s, a0.y, b0.y);
        r0.z = fmaf(s, a0.z, b0.z); r0.w = fmaf(s, a0.w, b0.w);
        r1.x = fmaf(s, a1.x, b1.x); r1.y = fmaf(s, a1.y, b1.y);
        r1.z = fmaf(s, a1.z, b1.z); r1.w = fmaf(s, a1.w, b1.w);
        r2.x = fmaf(s, a2.x, b2.x); r2.y = fmaf(s, a2.y, b2.y);
        r2.z = fmaf(s, a2.z, b2.z); r2.w = fmaf(s, a2.w, b2.w);
        r3.x = fmaf(s, a3.x, b3.x); r3.y = fmaf(s, a3.y, b3.y);
        r3.z = fmaf(s, a3.z, b3.z); r3.w = fmaf(s, a3.w, b3.w);

        o4[lane + (j+0)*64] = r0;
        o4[lane + (j+1)*64] = r1;
        o4[lane + (j+2)*64] = r2;
        o4[lane + (j+3)*64] = r3;
    }
}

extern "C" void kernel_launch(void* const* d_in, const int* in_sizes, int n_in,
                              void* d_out, int out_size, void* d_ws, size_t ws_size,
                              hipStream_t stream) {
    const float* v = (const float*)d_in[0];
    const float* z = (const float*)d_in[1];
    float* out = (float*)d_out;
    const int B = in_sizes[0] / L_DIM;            // 8192 rows
    const int grid = (B + WPB - 1) / WPB;         // 2048 blocks, 1 row per wave
    householder_kernel<<<grid, BLOCK, 0, stream>>>(v, z, out, B);
}

// Round 8
// 364.422 us; speedup vs baseline: 1.0900x; 1.0900x over previous
//
#include <hip/hip_runtime.h>

// Householder reflection, two-phase split:
//   S: s[b] = -2*(v[b].z[b])/(v[b].v[b])   (pure streaming reduce, RMSNorm-like)
//   E: out[b,:] = z[b,:] + s[b]*v[b,:]     (pure streaming elementwise, copy-like)
// R0-R7 post-mortem: every FUSED ideal-traffic structure (LDS-staged, block
// reg-staged, pipelined, wave-per-row) delivers 384MiB in ~110us = 3.65 TB/s
// (58% of the 6.29 TB/s copy ceiling), while re-read variants thrash L3.
// All >80%-BW references on this chip are 1R+1W streaming patterns. This
// splits the op into two such patterns; per-kernel counters discriminate
// "fusion-structure wall" vs "2R+1W machine wall".

#define L_DIM 4096
#define ROW_F4 (L_DIM / 4)          // 1024 float4 per row

typedef float f4 __attribute__((ext_vector_type(4)));

// ---------------- Kernel S: per-row scale (wave-per-row, read-only stream) ---
#define SBLOCK 256
#define SWPB (SBLOCK / 64)           // 4 rows per block
#define SNF4 (ROW_F4 / 64)           // 16 f4 per lane per array

__global__ __launch_bounds__(SBLOCK, 8) void hh_scales(
    const float* __restrict__ v,
    const float* __restrict__ z,
    float* __restrict__ s_out,
    int B)
{
    const int wave = threadIdx.x >> 6;
    const int lane = threadIdx.x & 63;
    const int row0 = blockIdx.x * SWPB + wave;
    const int rstride = gridDim.x * SWPB;

    for (int row = row0; row < B; row += rstride) {
        const f4* v4 = (const f4*)(v + (size_t)row * L_DIM);
        const f4* z4 = (const f4*)(z + (size_t)row * L_DIM);

        float vz0 = 0.f, vz1 = 0.f, vz2 = 0.f, vz3 = 0.f;
        float vv0 = 0.f, vv1 = 0.f, vv2 = 0.f, vv3 = 0.f;
        #pragma unroll
        for (int j = 0; j < SNF4; j += 4) {
            f4 a0 = v4[lane + (j+0)*64]; f4 b0 = z4[lane + (j+0)*64];
            f4 a1 = v4[lane + (j+1)*64]; f4 b1 = z4[lane + (j+1)*64];
            f4 a2 = v4[lane + (j+2)*64]; f4 b2 = z4[lane + (j+2)*64];
            f4 a3 = v4[lane + (j+3)*64]; f4 b3 = z4[lane + (j+3)*64];

            vz0 = fmaf(a0.x, b0.x, vz0); vz0 = fmaf(a0.y, b0.y, vz0);
            vz0 = fmaf(a0.z, b0.z, vz0); vz0 = fmaf(a0.w, b0.w, vz0);
            vv0 = fmaf(a0.x, a0.x, vv0); vv0 = fmaf(a0.y, a0.y, vv0);
            vv0 = fmaf(a0.z, a0.z, vv0); vv0 = fmaf(a0.w, a0.w, vv0);

            vz1 = fmaf(a1.x, b1.x, vz1); vz1 = fmaf(a1.y, b1.y, vz1);
            vz1 = fmaf(a1.z, b1.z, vz1); vz1 = fmaf(a1.w, b1.w, vz1);
            vv1 = fmaf(a1.x, a1.x, vv1); vv1 = fmaf(a1.y, a1.y, vv1);
            vv1 = fmaf(a1.z, a1.z, vv1); vv1 = fmaf(a1.w, a1.w, vv1);

            vz2 = fmaf(a2.x, b2.x, vz2); vz2 = fmaf(a2.y, b2.y, vz2);
            vz2 = fmaf(a2.z, b2.z, vz2); vz2 = fmaf(a2.w, b2.w, vz2);
            vv2 = fmaf(a2.x, a2.x, vv2); vv2 = fmaf(a2.y, a2.y, vv2);
            vv2 = fmaf(a2.z, a2.z, vv2); vv2 = fmaf(a2.w, a2.w, vv2);

            vz3 = fmaf(a3.x, b3.x, vz3); vz3 = fmaf(a3.y, b3.y, vz3);
            vz3 = fmaf(a3.z, b3.z, vz3); vz3 = fmaf(a3.w, b3.w, vz3);
            vv3 = fmaf(a3.x, a3.x, vv3); vv3 = fmaf(a3.y, a3.y, vv3);
            vv3 = fmaf(a3.z, a3.z, vv3); vv3 = fmaf(a3.w, a3.w, vv3);
        }
        float vz = (vz0 + vz1) + (vz2 + vz3);
        float vv = (vv0 + vv1) + (vv2 + vv3);

        #pragma unroll
        for (int off = 32; off > 0; off >>= 1) {
            vz += __shfl_xor(vz, off, 64);
            vv += __shfl_xor(vv, off, 64);
        }
        if (lane == 0) s_out[row] = -2.0f * vz / vv;
    }
}

// ---------------- Kernel E: apply (pure grid-stride stream, copy-like) ------
#define EBLOCK 256

__global__ __launch_bounds__(EBLOCK, 8) void hh_apply(
    const float* __restrict__ v,
    const float* __restrict__ z,
    const float* __restrict__ s,
    float* __restrict__ out,
    long n4)
{
    const f4* v4 = (const f4*)v;
    const f4* z4 = (const f4*)z;
    f4* o4 = (f4*)out;

    long i = (long)blockIdx.x * EBLOCK + threadIdx.x;
    const long stride = (long)gridDim.x * EBLOCK;

    for (; i < n4; i += stride) {
        f4 a = v4[i];
        f4 b = z4[i];
        const float sc = s[i >> 10];       // 1024 f4 per row; L1-hot
        f4 r;
        r.x = fmaf(sc, a.x, b.x);
        r.y = fmaf(sc, a.y, b.y);
        r.z = fmaf(sc, a.z, b.z);
        r.w = fmaf(sc, a.w, b.w);
        o4[i] = r;
    }
}

// ---------------- Fallback fused kernel (R6, known-good 110us) --------------
#define FBLOCK 256
#define FWPB (FBLOCK / 64)
#define FNF4 (ROW_F4 / 64)

__global__ __launch_bounds__(FBLOCK) void hh_fused(
    const float* __restrict__ v,
    const float* __restrict__ z,
    float* __restrict__ out,
    int B)
{
    const int wave = threadIdx.x >> 6;
    const int lane = threadIdx.x & 63;
    const int row = blockIdx.x * FWPB + wave;
    if (row >= B) return;
    const size_t base = (size_t)row * L_DIM;
    const f4* v4 = (const f4*)(v + base);
    const f4* z4 = (const f4*)(z + base);
    f4* o4 = (f4*)(out + base);

    f4 a[FNF4], b[FNF4];
    #pragma unroll
    for (int j = 0; j < FNF4; ++j) { a[j] = v4[lane + j*64]; b[j] = z4[lane + j*64]; }

    float vz = 0.f, vv = 0.f;
    #pragma unroll
    for (int j = 0; j < FNF4; ++j) {
        vz = fmaf(a[j].x, b[j].x, vz); vz = fmaf(a[j].y, b[j].y, vz);
        vz = fmaf(a[j].z, b[j].z, vz); vz = fmaf(a[j].w, b[j].w, vz);
        vv = fmaf(a[j].x, a[j].x, vv); vv = fmaf(a[j].y, a[j].y, vv);
        vv = fmaf(a[j].z, a[j].z, vv); vv = fmaf(a[j].w, a[j].w, vv);
    }
    #pragma unroll
    for (int off = 32; off > 0; off >>= 1) {
        vz += __shfl_xor(vz, off, 64);
        vv += __shfl_xor(vv, off, 64);
    }
    const float sc = -2.0f * vz / vv;
    #pragma unroll
    for (int j = 0; j < FNF4; ++j) {
        f4 r;
        r.x = fmaf(sc, a[j].x, b[j].x);
        r.y = fmaf(sc, a[j].y, b[j].y);
        r.z = fmaf(sc, a[j].z, b[j].z);
        r.w = fmaf(sc, a[j].w, b[j].w);
        o4[lane + j*64] = r;
    }
}

extern "C" void kernel_launch(void* const* d_in, const int* in_sizes, int n_in,
                              void* d_out, int out_size, void* d_ws, size_t ws_size,
                              hipStream_t stream) {
    const float* v = (const float*)d_in[0];
    const float* z = (const float*)d_in[1];
    float* out = (float*)d_out;
    const int B = in_sizes[0] / L_DIM;            // 8192 rows

    if (ws_size < (size_t)B * sizeof(float)) {
        // No workspace for scales: fall back to fused wave-per-row (110us).
        const int grid = (B + FWPB - 1) / FWPB;
        hh_fused<<<grid, FBLOCK, 0, stream>>>(v, z, out, B);
        return;
    }

    float* s = (float*)d_ws;                      // B floats = 32 KB

    const int sgrid = (B + SWPB - 1) / SWPB;      // 2048 blocks, 1 row/wave
    hh_scales<<<sgrid, SBLOCK, 0, stream>>>(v, z, s, B);

    const long n4 = (long)B * ROW_F4;             // 8M float4
    const int egrid = 2048;                        // grid-stride, 16 f4/thread
    hh_apply<<<egrid, EBLOCK, 0, stream>>>(v, z, s, out, n4);
}

// Round 9
// 363.561 us; speedup vs baseline: 1.0925x; 1.0024x over previous
//
#include <hip/hip_runtime.h>

// Householder reflection — DISCRIMINATION ROUND.
// R0-R8 consolidated: every row-chunked kernel (wave-per-row or block-per-row,
// staged or streamed, 27%-74% occupancy, VGPR 32-84) delivers ~2.4-2.5 TB/s
// of reads. R8 proved it with a PURE-READ reduction (hh_scales: 107us, no
// stores/LDS/barriers, 66% occ) while the grid-stride hh_apply beat 107us
// moving 1.5x the bytes. Remaining theories:
//   (a) DENSITY: row-chunked reads comb the DRAM (thousands of private 16KB
//       windows, ~1KB bursts each) -> page thrash; dense grid-stride is fast.
//   (b) MACHINE-WALL: a 2-read-stream mix caps at ~2.5 TB/s regardless.
// Probe: coherent grid-stride 2-stream dot-product read (identical fma mix to
// the real reduce, zero row bookkeeping). Then the known-good fused kernel
// rewrites ALL of out (correctness) and anchors the baseline (~110us).
// bench_dur ~= dispatch_sum + ~195us overhead (R0-R8 fit), so the probe's
// dur is recoverable even if absent from top-5.

#define L_DIM 4096
#define ROW_F4 (L_DIM / 4)          // 1024 float4 per row

typedef float f4 __attribute__((ext_vector_type(4)));

// ---------------- Probe: coherent grid-stride 2-stream pure read ------------
__global__ __launch_bounds__(256, 4) void probe_coherent_read(
    const float* __restrict__ v,
    const float* __restrict__ z,
    float* __restrict__ sink,     // = out; fully overwritten by hh_fused after
    long n4)
{
    const f4* v4 = (const f4*)v;
    const f4* z4 = (const f4*)z;
    const long stride = (long)gridDim.x * 256;
    long i = (long)blockIdx.x * 256 + threadIdx.x;

    float acc0 = 0.f, acc1 = 0.f, acc2 = 0.f, acc3 = 0.f;
    // 4-deep manual unroll: 8 loads in flight; whole-GPU window per iteration
    // is one dense contiguous ~32 MB region (the coherent pattern).
    for (; i + 3 * stride < n4; i += 4 * stride) {
        f4 a0 = v4[i];              f4 b0 = z4[i];
        f4 a1 = v4[i + stride];     f4 b1 = z4[i + stride];
        f4 a2 = v4[i + 2 * stride]; f4 b2 = z4[i + 2 * stride];
        f4 a3 = v4[i + 3 * stride]; f4 b3 = z4[i + 3 * stride];

        acc0 = fmaf(a0.x, b0.x, acc0); acc0 = fmaf(a0.y, b0.y, acc0);
        acc0 = fmaf(a0.z, b0.z, acc0); acc0 = fmaf(a0.w, b0.w, acc0);
        acc1 = fmaf(a1.x, b1.x, acc1); acc1 = fmaf(a1.y, b1.y, acc1);
        acc1 = fmaf(a1.z, b1.z, acc1); acc1 = fmaf(a1.w, b1.w, acc1);
        acc2 = fmaf(a2.x, b2.x, acc2); acc2 = fmaf(a2.y, b2.y, acc2);
        acc2 = fmaf(a2.z, b2.z, acc2); acc2 = fmaf(a2.w, b2.w, acc2);
        acc3 = fmaf(a3.x, b3.x, acc3); acc3 = fmaf(a3.y, b3.y, acc3);
        acc3 = fmaf(a3.z, b3.z, acc3); acc3 = fmaf(a3.w, b3.w, acc3);
    }
    for (; i < n4; i += stride) {
        f4 a = v4[i]; f4 b = z4[i];
        acc0 = fmaf(a.x, b.x, acc0); acc0 = fmaf(a.y, b.y, acc0);
        acc0 = fmaf(a.z, b.z, acc0); acc0 = fmaf(a.w, b.w, acc0);
    }

    float acc = (acc0 + acc1) + (acc2 + acc3);
    #pragma unroll
    for (int off = 32; off > 0; off >>= 1) acc += __shfl_xor(acc, off, 64);
    // Keep the loads live: one 4B store per wave (32 KB total, overwritten).
    if ((threadIdx.x & 63) == 0)
        sink[blockIdx.x * 4 + (threadIdx.x >> 6)] = acc;
}

// ---------------- Fused wave-per-row (known-good ~110us, writes ALL of out) -
#define FBLOCK 256
#define FWPB (FBLOCK / 64)
#define FNF4 (ROW_F4 / 64)

__global__ __launch_bounds__(FBLOCK) void hh_fused(
    const float* __restrict__ v,
    const float* __restrict__ z,
    float* __restrict__ out,
    int B)
{
    const int wave = threadIdx.x >> 6;
    const int lane = threadIdx.x & 63;
    const int row = blockIdx.x * FWPB + wave;
    if (row >= B) return;
    const size_t base = (size_t)row * L_DIM;
    const f4* v4 = (const f4*)(v + base);
    const f4* z4 = (const f4*)(z + base);
    f4* o4 = (f4*)(out + base);

    f4 a[FNF4], b[FNF4];
    #pragma unroll
    for (int j = 0; j < FNF4; ++j) { a[j] = v4[lane + j*64]; b[j] = z4[lane + j*64]; }

    float vz = 0.f, vv = 0.f;
    #pragma unroll
    for (int j = 0; j < FNF4; ++j) {
        vz = fmaf(a[j].x, b[j].x, vz); vz = fmaf(a[j].y, b[j].y, vz);
        vz = fmaf(a[j].z, b[j].z, vz); vz = fmaf(a[j].w, b[j].w, vz);
        vv = fmaf(a[j].x, a[j].x, vv); vv = fmaf(a[j].y, a[j].y, vv);
        vv = fmaf(a[j].z, a[j].z, vv); vv = fmaf(a[j].w, a[j].w, vv);
    }
    #pragma unroll
    for (int off = 32; off > 0; off >>= 1) {
        vz += __shfl_xor(vz, off, 64);
        vv += __shfl_xor(vv, off, 64);
    }
    const float sc = -2.0f * vz / vv;
    #pragma unroll
    for (int j = 0; j < FNF4; ++j) {
        f4 r;
        r.x = fmaf(sc, a[j].x, b[j].x);
        r.y = fmaf(sc, a[j].y, b[j].y);
        r.z = fmaf(sc, a[j].z, b[j].z);
        r.w = fmaf(sc, a[j].w, b[j].w);
        o4[lane + j*64] = r;
    }
}

extern "C" void kernel_launch(void* const* d_in, const int* in_sizes, int n_in,
                              void* d_out, int out_size, void* d_ws, size_t ws_size,
                              hipStream_t stream) {
    const float* v = (const float*)d_in[0];
    const float* z = (const float*)d_in[1];
    float* out = (float*)d_out;
    const int B = in_sizes[0] / L_DIM;            // 8192 rows
    const long n4 = (long)B * ROW_F4;             // 8M float4

    // 1) BW probe (coherent 2-stream read). Scribbles 32KB into out.
    probe_coherent_read<<<2048, 256, 0, stream>>>(v, z, out, n4);

    // 2) Known-good fused kernel rewrites every element of out (correctness
    //    preserved) and anchors the ~110us baseline in the same capture.
    const int fgrid = (B + FWPB - 1) / FWPB;
    hh_fused<<<fgrid, FBLOCK, 0, stream>>>(v, z, out, B);
}